// Round 15
// baseline (40.089 us; speedup 1.0000x reference)
//
#include <hip/hip_runtime.h>
#include <hip/hip_bf16.h>

#define FFN 2048
#define LN_EPS 1e-5f

typedef __attribute__((ext_vector_type(8))) short bf16x8;
typedef __attribute__((ext_vector_type(4))) float f32x4;

union FragU { bf16x8 v; unsigned u[4]; uint4 q; };

static __device__ __forceinline__ unsigned cvtpk(float lo, float hi) {
    unsigned r;
    asm("v_cvt_pk_bf16_f32 %0, %1, %2" : "=v"(r) : "v"(lo), "v"(hi));
    return r;
}

// cvt with |.| folded in via VOP3 input modifiers: one op = abs+cvt of 2 elements
static __device__ __forceinline__ unsigned cvtpk_abs(float lo, float hi) {
    unsigned r;
    asm("v_cvt_pk_bf16_f32 %0, |%1|, |%2|" : "=v"(r) : "v"(lo), "v"(hi));
    return r;
}

static __device__ __forceinline__ ushort to_bf16(float f) {   // RNE, finite inputs
    unsigned u = __float_as_uint(f);
    u += 0x7fffu + ((u >> 16) & 1u);
    return (ushort)(u >> 16);
}

static __device__ __forceinline__ float frombf(ushort u) {
    return __uint_as_float((unsigned)u << 16);
}

// ---------------- prep: packed per-lane 16x16x32 fragments ----------------
// Same verified layout as R3-R14; W2 records now hold bf16(W2/2) (exact halving).
__global__ __launch_bounds__(256) void tbq_prep(
    const float* __restrict__ W1, const float* __restrict__ b1,
    const float* __restrict__ W2, uint4* __restrict__ ws)
{
    const int idx = blockIdx.x * 256 + threadIdx.x;
    if (idx >= 6336) return;
    ushort v[8] = {0,0,0,0,0,0,0,0};
    if (idx < 4224) {
        const int rec = idx / 33, r = idx % 33;
        if (r) {
            const int l32 = r - 1, c = l32 & 15, g = l32 >> 4;
            const int s = rec & 1, cc = rec >> 1;
            const int f = cc * 32 + s * 16 + c;
            if (g == 0) {
                #pragma unroll
                for (int j = 0; j < 8; ++j) v[j] = to_bf16(W1[f * 8 + j]);
            } else {
                v[0] = to_bf16(b1[f]);
            }
        }
    } else {
        const int i2 = idx - 4224;
        const int rec = i2 / 33, r = i2 % 33;
        if (r) {
            const int l32 = r - 1, g = l32 >> 3, c = l32 & 7, cc = rec;
            #pragma unroll
            for (int j = 0; j < 8; ++j) {
                const int fl = 4 * g + (j & 3) + 16 * (j >> 2);
                v[j] = to_bf16(0.5f * W2[c * FFN + cc * 32 + fl]);   // halved W2
            }
        }
    }
    union { ushort s[8]; uint4 q; } pk;
    #pragma unroll
    for (int j = 0; j < 8; ++j) pk.s[j] = v[j];
    ws[idx] = pk.q;
}

// ---------------- prepM: M[e][k] = sum_f bf16(W2[e][f]/2) * bf16(W1[f][k] | b1[f]) ----------
// 72 entries (8e x 9k), one wave each: lane sums 32 f-values, shfl-reduce, lane0 writes.
__global__ __launch_bounds__(256) void tbq_prepM(
    const float* __restrict__ W1, const float* __restrict__ b1,
    const float* __restrict__ W2, float* __restrict__ M)
{
    const int w = blockIdx.x * 4 + (threadIdx.x >> 6);   // 0..71
    const int lane = threadIdx.x & 63;
    const int e = w / 9, k = w % 9;
    float acc = 0.0f;
    #pragma unroll 4
    for (int i = 0; i < 32; ++i) {
        const int f = lane + i * 64;
        const float w2v = frombf(to_bf16(0.5f * W2[e * FFN + f]));
        const float ov  = (k < 8) ? frombf(to_bf16(W1[f * 8 + k]))
                                  : frombf(to_bf16(b1[f]));
        acc += w2v * ov;
    }
    #pragma unroll
    for (int m = 32; m >= 1; m >>= 1) acc += __shfl_xor(acc, m, 64);
    if (lane == 0) M[w] = acc;
}

// ---------------- main: 128 tokens/block, 4 waves f-split, abs-half GEMM2 ----------------
__global__ __launch_bounds__(256) void tbq_mfma(
    const float* __restrict__ x,
    const float* __restrict__ Wq,
    const float* __restrict__ Wo,
    const float* __restrict__ b2,
    const float* __restrict__ g1,
    const float* __restrict__ beta1,
    const float* __restrict__ g2,
    const float* __restrict__ beta2,
    const uint4* __restrict__ ws,
    const float* __restrict__ M,
    float* __restrict__ out)
{
    __shared__ __align__(16) uint4 mS[128];           // 2KB  m (bf16) per token
    __shared__ __align__(16) float part[4][128][8];   // 16KB per-wave partial ffn

    const int tid  = threadIdx.x;
    const int lane = tid & 63;
    const int wv   = tid >> 6;
    const int c    = lane & 15;
    const int g    = lane >> 4;
    const int tok0 = blockIdx.x * 128;

    // per-lane packed-record slot offsets (uint4 units; 0 -> zero slot)
    const int o1 = (lane < 32) ? (1 + lane) : 0;
    const int o2 = ((lane & 8) == 0) ? (1 + ((lane >> 4) << 3) + (lane & 7)) : 0;
    const int cc0 = wv * 16;

    // ---- pipeline prologue: issue loads for chunks 0,1,2 into slots 0,1,2 ----
    FragU F0[4], F1[4], A2[4];
    #pragma unroll
    for (int p = 0; p < 3; ++p) {
        const int cc = cc0 + p;
        F0[p].q = (ws + cc * 66)[o1];
        F1[p].q = (ws + cc * 66 + 33)[o1];
        A2[p].q = (ws + 4224 + cc * 33)[o2];
    }

    // ---- prefix: threads 0-127, one thread per token ----
    float h[8];
    float m[8];
    if (tid < 128) {
        const int t = tok0 + tid;
        const float4* xr = (const float4*)(x + (size_t)t * 8);
        float4 xa = xr[0], xb = xr[1];
        float xv[8] = {xa.x, xa.y, xa.z, xa.w, xb.x, xb.y, xb.z, xb.w};

        float qm[8];
        {
            float cp = 1.0f;
            #pragma unroll
            for (int f = 0; f < 8; ++f) {
                float acc = 0.0f;
                #pragma unroll
                for (int e = 0; e < 8; ++e) acc += xv[e] * Wq[f * 8 + e];
                cp *= __cosf(acc);
                qm[f] = cp;
            }
        }
        float mu = 0.0f;
        #pragma unroll
        for (int f = 0; f < 8; ++f) {
            float acc = 0.0f;
            #pragma unroll
            for (int e = 0; e < 8; ++e) acc += qm[e] * Wo[f * 8 + e];
            h[f] = xv[f] + acc;
            mu += h[f];
        }
        mu *= 0.125f;
        float var = 0.0f;
        #pragma unroll
        for (int i = 0; i < 8; ++i) { float d = h[i] - mu; var += d * d; }
        var *= 0.125f;
        float rs = rsqrtf(var + LN_EPS);
        #pragma unroll
        for (int i = 0; i < 8; ++i) h[i] = (h[i] - mu) * rs * g1[i] + beta1[i];

        {
            float cp = 1.0f;
            #pragma unroll
            for (int i = 0; i < 8; ++i) { cp *= __cosf(h[i]); m[i] = cp; }
        }
        uint4 mq;
        mq.x = cvtpk(m[0], m[1]); mq.y = cvtpk(m[2], m[3]);
        mq.z = cvtpk(m[4], m[5]); mq.w = cvtpk(m[6], m[7]);
        mS[tid] = mq;
    }
    __syncthreads();

    // ---- B1 fragments: 8 token-tiles (k=8g+j; g0: m, g1 j0: bias row 1.0) ----
    FragU B1[8];
    #pragma unroll
    for (int T = 0; T < 8; ++T) {
        uint4 mr = mS[T * 16 + c];
        B1[T].u[0] = (g == 0) ? mr.x : ((g == 1) ? 0x00003F80u : 0u);
        B1[T].u[1] = (g == 0) ? mr.y : 0u;
        B1[T].u[2] = (g == 0) ? mr.z : 0u;
        B1[T].u[3] = (g == 0) ? mr.w : 0u;
    }

    // ---- pinned zero C-tuple ----
    f32x4 z4 = {0.f, 0.f, 0.f, 0.f};
    asm volatile("" : "+v"(z4));

    // ---- FFN abs-half: 16 chunks, 4-slot rotation / distance-3 prefetch ----
    f32x4 acc[8] = {{0,0,0,0},{0,0,0,0},{0,0,0,0},{0,0,0,0},
                    {0,0,0,0},{0,0,0,0},{0,0,0,0},{0,0,0,0}};

    #pragma unroll
    for (int i = 0; i < 16; ++i) {
        const int cur = i & 3;
        if (i + 3 < 16) {
            const int nslot = (i + 3) & 3;
            const int cc = cc0 + i + 3;
            F0[nslot].q = (ws + cc * 66)[o1];
            F1[nslot].q = (ws + cc * 66 + 33)[o1];
            A2[nslot].q = (ws + 4224 + cc * 33)[o2];
        }
        __builtin_amdgcn_s_setprio(1);
        #pragma unroll
        for (int T = 0; T < 8; ++T) {
            f32x4 c0 = __builtin_amdgcn_mfma_f32_16x16x32_bf16(F0[cur].v, B1[T].v, z4, 0, 0, 0);
            f32x4 c1 = __builtin_amdgcn_mfma_f32_16x16x32_bf16(F1[cur].v, B1[T].v, z4, 0, 0, 0);
            FragU B2;                             // |hid| in bf16, one op per pair
            B2.u[0] = cvtpk_abs(c0[0], c0[1]);
            B2.u[1] = cvtpk_abs(c0[2], c0[3]);
            B2.u[2] = cvtpk_abs(c1[0], c1[1]);
            B2.u[3] = cvtpk_abs(c1[2], c1[3]);
            acc[T] = __builtin_amdgcn_mfma_f32_16x16x32_bf16(A2[cur].v, B2.v, acc[T], 0, 0, 0);
        }
        __builtin_amdgcn_s_setprio(0);
    }

    // ---- write partial fragments: part[wv][tok][e] ----
    if (g < 2) {
        #pragma unroll
        for (int T = 0; T < 8; ++T) {
            *(f32x4*)&part[wv][T * 16 + c][4 * g] = acc[T];
        }
    }
    __syncthreads();

    // ---- threads 0-127: reduce partials + linear term M*m_hat + LN2 + store ----
    if (tid < 128) {
        // bf16-rounded m (to match the MFMA path) + bias slot
        float mb[9];
        #pragma unroll
        for (int k = 0; k < 8; ++k) mb[k] = frombf(to_bf16(m[k]));
        mb[8] = 1.0f;

        float ffnv[8];
        #pragma unroll
        for (int e = 0; e < 8; ++e) {
            float s = part[0][tid][e] + part[1][tid][e]
                    + part[2][tid][e] + part[3][tid][e];   // = 1/2 W2 |hid|
            float lin = 0.0f;
            #pragma unroll
            for (int k = 0; k < 9; ++k) lin += M[e * 9 + k] * mb[k];  // = 1/2 W2 hid
            ffnv[e] = s + lin;
        }

        float o[8];
        float mu2 = 0.0f;
        #pragma unroll
        for (int i = 0; i < 8; ++i) { o[i] = h[i] + ffnv[i] + b2[i]; mu2 += o[i]; }
        mu2 *= 0.125f;
        float v2 = 0.0f;
        #pragma unroll
        for (int i = 0; i < 8; ++i) { float d = o[i] - mu2; v2 += d * d; }
        v2 *= 0.125f;
        float rs2 = rsqrtf(v2 + LN_EPS);

        float res[8];
        #pragma unroll
        for (int i = 0; i < 8; ++i) res[i] = (o[i] - mu2) * rs2 * g2[i] + beta2[i];

        float4* orow = (float4*)(out + (size_t)(tok0 + tid) * 8);
        orow[0] = make_float4(res[0], res[1], res[2], res[3]);
        orow[1] = make_float4(res[4], res[5], res[6], res[7]);
    }
}

extern "C" void kernel_launch(void* const* d_in, const int* in_sizes, int n_in,
                              void* d_out, int out_size, void* d_ws, size_t ws_size,
                              hipStream_t stream) {
    const float* x     = (const float*)d_in[0];
    const float* Wq    = (const float*)d_in[1];
    const float* Wo    = (const float*)d_in[2];
    const float* W1    = (const float*)d_in[3];
    const float* b1    = (const float*)d_in[4];
    const float* W2    = (const float*)d_in[5];
    const float* b2    = (const float*)d_in[6];
    const float* g1    = (const float*)d_in[7];
    const float* beta1 = (const float*)d_in[8];
    const float* g2    = (const float*)d_in[9];
    const float* beta2 = (const float*)d_in[10];
    float* out = (float*)d_out;
    uint4* ws = (uint4*)d_ws;                 // frags: 6336*16 B
    float* M  = (float*)(ws + 6336);          // + 72 floats

    tbq_prep<<<25, 256, 0, stream>>>(W1, b1, W2, ws);
    tbq_prepM<<<18, 256, 0, stream>>>(W1, b1, W2, M);

    const int ntok = in_sizes[0] / 8;      // 131072
    const int grid = ntok / 128;           // 1024 blocks, 4 waves f-split
    tbq_mfma<<<grid, 256, 0, stream>>>(x, Wq, Wo, b2, g1, beta1, g2, beta2, ws, M, out);
}

// Round 16
// 34.948 us; speedup vs baseline: 1.1471x; 1.1471x over previous
//
#include <hip/hip_runtime.h>
#include <hip/hip_bf16.h>

#define FFN 2048
#define LN_EPS 1e-5f

typedef __attribute__((ext_vector_type(8))) short bf16x8;
typedef __attribute__((ext_vector_type(4))) short bf16x4;
typedef __attribute__((ext_vector_type(4))) float f32x4;

union FragU  { bf16x8 v; unsigned u[4]; uint4 q; };
union Frag2U { bf16x4 v; unsigned u[2]; uint2 d; };

static __device__ __forceinline__ unsigned cvtpk(float lo, float hi) {
    unsigned r;
    asm("v_cvt_pk_bf16_f32 %0, %1, %2" : "=v"(r) : "v"(lo), "v"(hi));
    return r;
}

static __device__ __forceinline__ ushort to_bf16(float f) {   // RNE, finite inputs
    unsigned u = __float_as_uint(f);
    u += 0x7fffu + ((u >> 16) & 1u);
    return (ushort)(u >> 16);
}
static __device__ __forceinline__ float frombf(ushort u) {
    return __uint_as_float((unsigned)u << 16);
}
static __device__ __forceinline__ unsigned pk2u(ushort a, ushort b) {
    return (unsigned)a | ((unsigned)b << 16);
}

// ws layout:
//  uint4  [0 .. 2111]        pW2: 64 recs x 33 uint4 (slot0=zeros; slots1..32: lane l32:
//                            g=l32>>3,c=l32&7; v[j]=bf16(0.5*W2[c*FFN+cc*32+4g+(j&3)+16*(j>>2)]))
//  uint2  [4224 .. 10623]    pW1x16: 128 recs (cc*2+s) x 50 uint2:
//                            slot0=0; 1..32: l32=c+16*gg -> (W1[f][4gg..4gg+3]) bf16;
//                            33..48: c -> (b1[f],0); 49: 0.   f = cc*32+s*16+c
//  float  [21248 .. 21319]   M[e*9+k] = sum_f bf16(W2[e][f]/2)*bf16(W1[f][k] | b1[f])
__global__ __launch_bounds__(256) void tbq_prep(
    const float* __restrict__ W1, const float* __restrict__ b1,
    const float* __restrict__ W2, uint4* __restrict__ ws)
{
    const int b = blockIdx.x;
    if (b < 34) {
        const int idx = b * 256 + threadIdx.x;
        if (idx < 2112) {                       // pW2 records (R15-verified values)
            const int rec = idx / 33, r = idx % 33;
            ushort v[8] = {0,0,0,0,0,0,0,0};
            if (r) {
                const int l32 = r - 1, g = l32 >> 3, c = l32 & 7, cc = rec;
                #pragma unroll
                for (int j = 0; j < 8; ++j) {
                    const int fl = 4 * g + (j & 3) + 16 * (j >> 2);
                    v[j] = to_bf16(0.5f * W2[c * FFN + cc * 32 + fl]);
                }
            }
            union { ushort s[8]; uint4 q; } pk;
            #pragma unroll
            for (int j = 0; j < 8; ++j) pk.s[j] = v[j];
            ws[idx] = pk.q;
        } else if (idx < 8512) {                // pW1x16 records
            const int i2 = idx - 2112;
            const int rec = i2 / 50, r = i2 % 50;
            const int s = rec & 1, cc = rec >> 1;
            uint2 val = make_uint2(0u, 0u);
            if (r >= 1 && r <= 32) {
                const int l32 = r - 1, c = l32 & 15, gg = l32 >> 4;
                const int f = cc * 32 + s * 16 + c;
                val.x = pk2u(to_bf16(W1[f * 8 + 4 * gg + 0]), to_bf16(W1[f * 8 + 4 * gg + 1]));
                val.y = pk2u(to_bf16(W1[f * 8 + 4 * gg + 2]), to_bf16(W1[f * 8 + 4 * gg + 3]));
            } else if (r >= 33 && r <= 48) {
                const int c = r - 33;
                const int f = cc * 32 + s * 16 + c;
                val.x = pk2u(to_bf16(b1[f]), 0);
            }
            ((uint2*)ws)[4224 + i2] = val;
        }
    } else {                                    // M reduction (R15-verified)
        const int w = (b - 34) * 4 + (threadIdx.x >> 6);   // 0..71
        const int lane = threadIdx.x & 63;
        const int e = w / 9, k = w % 9;
        float acc = 0.0f;
        #pragma unroll 4
        for (int i = 0; i < 32; ++i) {
            const int f = lane + i * 64;
            const float w2v = frombf(to_bf16(0.5f * W2[e * FFN + f]));
            const float ov  = (k < 8) ? frombf(to_bf16(W1[f * 8 + k]))
                                      : frombf(to_bf16(b1[f]));
            acc += w2v * ov;
        }
        #pragma unroll
        for (int m = 32; m >= 1; m >>= 1) acc += __shfl_xor(acc, m, 64);
        if (lane == 0) ((float*)ws)[21248 + w] = acc;
    }
}

// T-body: 2x GEMM1 (16x16x16, K=9 real of 16) -> |.|+bf16 pack -> GEMM2 (16x16x32 acc).
// All hazards manual (R14-proven pattern); banks A/B decouple consecutive bodies.
#define TB_A(ACC, F0V, F1V, A2V, B1V)                                                  \
    asm volatile(                                                                      \
        "v_mfma_f32_16x16x16_bf16 v[40:43], %[f0], %[b1], %[z]\n\t"                    \
        "v_mfma_f32_16x16x16_bf16 v[44:47], %[f1], %[b1], %[z]\n\t"                    \
        "s_nop 7\n\t"                                                                  \
        "s_nop 7\n\t"                                                                  \
        "v_cvt_pk_bf16_f32 v48, |v40|, |v41|\n\t"                                      \
        "v_cvt_pk_bf16_f32 v49, |v42|, |v43|\n\t"                                      \
        "v_cvt_pk_bf16_f32 v50, |v44|, |v45|\n\t"                                      \
        "v_cvt_pk_bf16_f32 v51, |v46|, |v47|\n\t"                                      \
        "s_nop 3\n\t"                                                                  \
        "v_mfma_f32_16x16x32_bf16 %[acc], %[a2], v[48:51], %[acc]"                     \
        : [acc] "+v"(ACC)                                                              \
        : [f0] "v"(F0V), [f1] "v"(F1V), [a2] "v"(A2V), [b1] "v"(B1V), [z] "v"(z4)      \
        : "v40","v41","v42","v43","v44","v45","v46","v47","v48","v49","v50","v51")

#define TB_B(ACC, F0V, F1V, A2V, B1V)                                                  \
    asm volatile(                                                                      \
        "v_mfma_f32_16x16x16_bf16 v[52:55], %[f0], %[b1], %[z]\n\t"                    \
        "v_mfma_f32_16x16x16_bf16 v[56:59], %[f1], %[b1], %[z]\n\t"                    \
        "s_nop 7\n\t"                                                                  \
        "s_nop 7\n\t"                                                                  \
        "v_cvt_pk_bf16_f32 v60, |v52|, |v53|\n\t"                                      \
        "v_cvt_pk_bf16_f32 v61, |v54|, |v55|\n\t"                                      \
        "v_cvt_pk_bf16_f32 v62, |v56|, |v57|\n\t"                                      \
        "v_cvt_pk_bf16_f32 v63, |v58|, |v59|\n\t"                                      \
        "s_nop 3\n\t"                                                                  \
        "v_mfma_f32_16x16x32_bf16 %[acc], %[a2], v[60:63], %[acc]"                     \
        : [acc] "+v"(ACC)                                                              \
        : [f0] "v"(F0V), [f1] "v"(F1V), [a2] "v"(A2V), [b1] "v"(B1V), [z] "v"(z4)      \
        : "v52","v53","v54","v55","v56","v57","v58","v59","v60","v61","v62","v63")

// ---------------- main: 128 tokens/block, 4 waves f-split ----------------
__global__ __launch_bounds__(256) void tbq_mfma(
    const float* __restrict__ x,
    const float* __restrict__ Wq,
    const float* __restrict__ Wo,
    const float* __restrict__ b2,
    const float* __restrict__ g1,
    const float* __restrict__ beta1,
    const float* __restrict__ g2,
    const float* __restrict__ beta2,
    const uint4* __restrict__ ws,
    float* __restrict__ out)
{
    __shared__ __align__(16) uint4 mS[128];           // 2KB  m (bf16) per token
    __shared__ __align__(16) float part[4][128][8];   // 16KB per-wave partial ffn

    const int tid  = threadIdx.x;
    const int lane = tid & 63;
    const int wv   = tid >> 6;
    const int c    = lane & 15;
    const int g    = lane >> 4;
    const int tok0 = blockIdx.x * 128;

    const uint2* ws2 = (const uint2*)ws;
    const float* M   = (const float*)ws + 21248;

    // per-lane slot offsets
    const int o1x = (g < 2) ? (1 + c + 16 * g) : ((g == 2) ? (33 + c) : 0);   // uint2 units
    const int o2  = ((lane & 8) == 0) ? (1 + ((lane >> 4) << 3) + (lane & 7)) : 0;  // uint4
    const int cc0 = wv * 16;

    // ---- pipeline prologue: chunks 0,1,2 into slots 0,1,2 ----
    Frag2U F0[4], F1[4];
    FragU  A2[4];
    #pragma unroll
    for (int p = 0; p < 3; ++p) {
        const int cc = cc0 + p;
        F0[p].d = ws2[4224 + (cc * 2 + 0) * 50 + o1x];
        F1[p].d = ws2[4224 + (cc * 2 + 1) * 50 + o1x];
        A2[p].q = (ws + cc * 33)[o2];
    }

    // ---- prefix: threads 0-127, one thread per token ----
    float h[8], m[8];
    if (tid < 128) {
        const int t = tok0 + tid;
        const float4* xr = (const float4*)(x + (size_t)t * 8);
        float4 xa = xr[0], xb = xr[1];
        float xv[8] = {xa.x, xa.y, xa.z, xa.w, xb.x, xb.y, xb.z, xb.w};

        float qm[8];
        {
            float cp = 1.0f;
            #pragma unroll
            for (int f = 0; f < 8; ++f) {
                float acc = 0.0f;
                #pragma unroll
                for (int e = 0; e < 8; ++e) acc += xv[e] * Wq[f * 8 + e];
                cp *= __cosf(acc);
                qm[f] = cp;
            }
        }
        float mu = 0.0f;
        #pragma unroll
        for (int f = 0; f < 8; ++f) {
            float acc = 0.0f;
            #pragma unroll
            for (int e = 0; e < 8; ++e) acc += qm[e] * Wo[f * 8 + e];
            h[f] = xv[f] + acc;
            mu += h[f];
        }
        mu *= 0.125f;
        float var = 0.0f;
        #pragma unroll
        for (int i = 0; i < 8; ++i) { float d = h[i] - mu; var += d * d; }
        var *= 0.125f;
        float rs = rsqrtf(var + LN_EPS);
        #pragma unroll
        for (int i = 0; i < 8; ++i) h[i] = (h[i] - mu) * rs * g1[i] + beta1[i];

        {
            float cp = 1.0f;
            #pragma unroll
            for (int i = 0; i < 8; ++i) { cp *= __cosf(h[i]); m[i] = cp; }
        }
        uint4 mq;
        mq.x = cvtpk(m[0], m[1]); mq.y = cvtpk(m[2], m[3]);
        mq.z = cvtpk(m[4], m[5]); mq.w = cvtpk(m[6], m[7]);
        mS[tid] = mq;
    }
    __syncthreads();

    // ---- B1 fragments (x16: 2 regs): slots (gg,j): gg<2 -> m[4gg+j]; gg=2,j=0 -> 1.0 ----
    Frag2U B1[8];
    #pragma unroll
    for (int T = 0; T < 8; ++T) {
        uint4 mr = mS[T * 16 + c];
        unsigned u0 = (g == 0) ? mr.x : ((g == 1) ? mr.z : ((g == 2) ? 0x00003F80u : 0u));
        unsigned u1 = (g == 0) ? mr.y : ((g == 1) ? mr.w : 0u);
        B1[T].u[0] = u0;
        B1[T].u[1] = u1;
    }

    // ---- pinned zero C-tuple ----
    f32x4 z4 = {0.f, 0.f, 0.f, 0.f};
    asm volatile("" : "+v"(z4));

    f32x4 acc[8] = {{0,0,0,0},{0,0,0,0},{0,0,0,0},{0,0,0,0},
                    {0,0,0,0},{0,0,0,0},{0,0,0,0},{0,0,0,0}};
    asm volatile("s_nop 3" ::: "memory");   // VALU writes -> asm MFMA reads

    // ---- FFN abs-half: 16 chunks, 4-slot rotation / distance-3 prefetch ----
    #pragma unroll
    for (int i = 0; i < 16; ++i) {
        const int cur = i & 3;
        if (i + 3 < 16) {
            const int ns = (i + 3) & 3;
            const int cc = cc0 + i + 3;
            F0[ns].d = ws2[4224 + (cc * 2 + 0) * 50 + o1x];
            F1[ns].d = ws2[4224 + (cc * 2 + 1) * 50 + o1x];
            A2[ns].q = (ws + cc * 33)[o2];
        }
        __builtin_amdgcn_s_setprio(1);
        TB_A(acc[0], F0[cur].v, F1[cur].v, A2[cur].v, B1[0].v);
        TB_B(acc[1], F0[cur].v, F1[cur].v, A2[cur].v, B1[1].v);
        TB_A(acc[2], F0[cur].v, F1[cur].v, A2[cur].v, B1[2].v);
        TB_B(acc[3], F0[cur].v, F1[cur].v, A2[cur].v, B1[3].v);
        TB_A(acc[4], F0[cur].v, F1[cur].v, A2[cur].v, B1[4].v);
        TB_B(acc[5], F0[cur].v, F1[cur].v, A2[cur].v, B1[5].v);
        TB_A(acc[6], F0[cur].v, F1[cur].v, A2[cur].v, B1[6].v);
        TB_B(acc[7], F0[cur].v, F1[cur].v, A2[cur].v, B1[7].v);
        __builtin_amdgcn_s_setprio(0);
    }
    asm volatile("s_nop 7\n\ts_nop 7" ::: "memory");   // MFMA writes -> LDS-store reads

    // ---- write partial fragments: part[wv][tok][e] ----
    if (g < 2) {
        #pragma unroll
        for (int T = 0; T < 8; ++T) {
            *(f32x4*)&part[wv][T * 16 + c][4 * g] = acc[T];
        }
    }
    __syncthreads();

    // ---- threads 0-127: reduce partials + linear term M*m_hat + LN2 + store ----
    if (tid < 128) {
        float mb[9];
        #pragma unroll
        for (int k = 0; k < 8; ++k) mb[k] = frombf(to_bf16(m[k]));
        mb[8] = 1.0f;

        float ffnv[8];
        #pragma unroll
        for (int e = 0; e < 8; ++e) {
            float s = part[0][tid][e] + part[1][tid][e]
                    + part[2][tid][e] + part[3][tid][e];   // = 1/2 W2 |hid|
            float lin = 0.0f;
            #pragma unroll
            for (int k = 0; k < 9; ++k) lin += M[e * 9 + k] * mb[k];  // = 1/2 W2 hid
            ffnv[e] = s + lin;
        }

        float o[8];
        float mu2 = 0.0f;
        #pragma unroll
        for (int i = 0; i < 8; ++i) { o[i] = h[i] + ffnv[i] + b2[i]; mu2 += o[i]; }
        mu2 *= 0.125f;
        float v2 = 0.0f;
        #pragma unroll
        for (int i = 0; i < 8; ++i) { float d = o[i] - mu2; v2 += d * d; }
        v2 *= 0.125f;
        float rs2 = rsqrtf(v2 + LN_EPS);

        float res[8];
        #pragma unroll
        for (int i = 0; i < 8; ++i) res[i] = (o[i] - mu2) * rs2 * g2[i] + beta2[i];

        float4* orow = (float4*)(out + (size_t)(tok0 + tid) * 8);
        orow[0] = make_float4(res[0], res[1], res[2], res[3]);
        orow[1] = make_float4(res[4], res[5], res[6], res[7]);
    }
}

extern "C" void kernel_launch(void* const* d_in, const int* in_sizes, int n_in,
                              void* d_out, int out_size, void* d_ws, size_t ws_size,
                              hipStream_t stream) {
    const float* x     = (const float*)d_in[0];
    const float* Wq    = (const float*)d_in[1];
    const float* Wo    = (const float*)d_in[2];
    const float* W1    = (const float*)d_in[3];
    const float* b1    = (const float*)d_in[4];
    const float* W2    = (const float*)d_in[5];
    const float* b2    = (const float*)d_in[6];
    const float* g1    = (const float*)d_in[7];
    const float* beta1 = (const float*)d_in[8];
    const float* g2    = (const float*)d_in[9];
    const float* beta2 = (const float*)d_in[10];
    float* out = (float*)d_out;
    uint4* ws = (uint4*)d_ws;   // ~85.3 KB used

    tbq_prep<<<52, 256, 0, stream>>>(W1, b1, W2, ws);   // 34 rec-blocks + 18 M-blocks

    const int ntok = in_sizes[0] / 8;      // 131072
    const int grid = ntok / 128;           // 1024 blocks, 4 waves f-split
    tbq_mfma<<<grid, 256, 0, stream>>>(x, Wq, Wo, b2, g1, beta1, g2, beta2, ws, out);
}